// Round 3
// baseline (166.718 us; speedup 1.0000x reference)
//
#include <hip/hip_runtime.h>
#include <hip/hip_bf16.h>

// ---------------------------------------------------------------------------
// Round 3: operand-swapped formulation (round-2 structure), combine-shuffle
// quad-selection FIXED.
//   conv GEMM:  C[out_ch96][spatial] = W_hat (A) x xT (B), per phase.
//     A frag: lane m = out_ch (l&31), k = 8*(l>>5)+j  (symmetric to the
//             round-1-verified B layout).
//     B frag: lane n = x-position (l&31), k = 8 consecutive channels -> one
//             16B global load from x-padded, channel-fastest xT. No LDS.
//   C rows = channels => C is directly the B operand of the combine GEMM via
//   half-wave __shfl_xor(32). For step s2=2e+f, half h: frag channels
//   16e+8h+[0,8) live in reg-quad (2e+h) of BOTH halves => each lane USES
//   quad 2e+h and SENDS quad 2e+(1-h) (receiver gets sender's 2e+h). This
//   was the round-2 bug (sent own-quad instead).
//   One wave = one (z,y) row x one phase: acc = 48 regs, launch_bounds(256,4).
//   z/y halo = wave-uniform tap skip; x halo = padded xT [32][32][34][64].
// ---------------------------------------------------------------------------

typedef __bf16 bf16x8 __attribute__((ext_vector_type(8)));
typedef float f32x16 __attribute__((ext_vector_type(16)));

__device__ inline unsigned short f2bf(float f) {
  unsigned int u = __float_as_uint(f);
  u += 0x7FFFu + ((u >> 16) & 1u);
  return (unsigned short)(u >> 16);
}
__device__ inline bf16x8 bc16(uint4 v) { return __builtin_bit_cast(bf16x8, v); }

#define ROWS 2176  // 34 * 64 shorts per (z,y) row of padded xT

__device__ inline float ucoef(int abit, int k, int jbit, float alpha) {
  if (abit == 0) return (k == 0) ? (jbit ? alpha : 1.f - alpha) : (jbit ? 1.f : 0.f);
  return (k == 2) ? (jbit ? 1.f - alpha : alpha) : (jbit ? 0.f : 1.f);
}

// ---------------- k_prep: transpose+pad / weights / combine-weights ---------
__global__ void k_prep(const float* __restrict__ x,
                       const float* __restrict__ w_def,
                       const float* __restrict__ b_def,
                       const float* __restrict__ bn1_g,
                       const float* __restrict__ bn1_b,
                       const float* __restrict__ bn1_m,
                       const float* __restrict__ bn1_v,
                       const float* __restrict__ w_comb,
                       const float* __restrict__ b_comb,
                       const float* __restrict__ bn2_g,
                       const float* __restrict__ bn2_b,
                       const float* __restrict__ bn2_m,
                       const float* __restrict__ bn2_v,
                       unsigned short* __restrict__ xTpad,
                       unsigned short* __restrict__ W_sw,
                       unsigned short* __restrict__ W2_sw,
                       float* __restrict__ bias1,
                       float* __restrict__ bias2) {
  __shared__ unsigned short t[64][65];
  int bid = blockIdx.x;
  int tid = threadIdx.x;
  if (bid < 512) {
    // transpose x [64][32768] f32 -> xTpad [32][32][34][64] bf16 (x-dim pad)
    int s0 = bid * 64;
    int lane = tid & 63;
    int grp = tid >> 6;
    int z = s0 >> 10;
    int y0 = (s0 >> 5) & 31;
#pragma unroll
    for (int c = grp; c < 64; c += 4)
      t[c][lane] = f2bf(x[c * 32768 + s0 + lane]);
    // zero the x-pads for this block's two (z,y) rows
    {
      int row = tid >> 7, side = (tid >> 6) & 1, ch = tid & 63;
      xTpad[(z * 32 + y0 + row) * ROWS + side * (33 * 64) + ch] = 0;
    }
    __syncthreads();
#pragma unroll
    for (int s = grp; s < 64; s += 4)
      xTpad[(z * 32 + y0 + (s >> 5)) * ROWS + ((s & 31) + 1) * 64 + lane] =
          t[lane][s];
  } else if (bid < 2048) {
    // phase-collapsed, BN1-folded conv weights (A-operand layout)
    int e = (bid - 512) * 256 + tid;  // < 393216
    int j = e & 7;
    int lane = (e >> 3) & 63;
    int idx = e >> 9;
    int nt = idx % 3;
    idx /= 3;
    int s = idx & 31;
    int p = idx >> 5;
    int o = lane & 31;
    int kk = 16 * s + ((lane >> 5) << 3) + j;
    int tap = kk >> 6, ch = kk & 63;
    int jz = (tap >> 2) & 1, jy = (tap >> 1) & 1, jx = tap & 1;
    int a = (p >> 2) & 1, b = (p >> 1) & 1, cp = p & 1;
    float alpha = (nt == 0) ? 0.f : ((nt == 1) ? 0.4f : 0.7f);
    const float* wb = w_def + (o * 64 + ch) * 27;
    float sum = 0.f;
    for (int kz = 0; kz < 3; ++kz) {
      float uz = ucoef(a, kz, jz, alpha);
      if (uz == 0.f) continue;
      for (int ky = 0; ky < 3; ++ky) {
        float uy = ucoef(b, ky, jy, alpha);
        if (uy == 0.f) continue;
        float uzy = uz * uy;
        for (int kx = 0; kx < 3; ++kx) {
          float ux = ucoef(cp, kx, jx, alpha);
          if (ux != 0.f) sum += wb[kz * 9 + ky * 3 + kx] * uzy * ux;
        }
      }
    }
    float s1 = bn1_g[o] * rsqrtf(bn1_v[o] + 1e-5f);
    W_sw[e] = f2bf(sum * s1);
  } else {
    // combine weights (A-operand layout) + folded biases
    for (int e = tid; e < 3072; e += 256) {
      int j = e & 7;
      int lane = (e >> 3) & 63;
      int s2 = e >> 9;
      int n = lane & 31;
      int k = 16 * s2 + ((lane >> 5) << 3) + j;
      float sc2 = bn2_g[n] * rsqrtf(bn2_v[n] + 1e-5f);
      W2_sw[e] = f2bf(w_comb[n * 96 + k] * sc2);
    }
    if (tid < 32) {
      float s1 = bn1_g[tid] * rsqrtf(bn1_v[tid] + 1e-5f);
      bias1[tid] = (b_def[tid] - bn1_m[tid]) * s1 + bn1_b[tid];
      float s2 = bn2_g[tid] * rsqrtf(bn2_v[tid] + 1e-5f);
      bias2[tid] = (b_comb[tid] - bn2_m[tid]) * s2 + bn2_b[tid];
    }
  }
}

// ---------------- k_main: conv GEMM + fused combine, zero LDS ---------------
__launch_bounds__(256, 4)
__global__ void k_main(const unsigned short* __restrict__ xTpad,
                       const unsigned short* __restrict__ W_sw,
                       const unsigned short* __restrict__ W2_sw,
                       const float* __restrict__ bias1f,
                       const float* __restrict__ bias2f,
                       float* __restrict__ out) {
  int tid = threadIdx.x;
  int lane = tid & 63;
  int wv = tid >> 6;
  int n = lane & 31;
  int h = lane >> 5;
  int bid = blockIdx.x;
  // bid = u*16 + cp*8 + v : cp-siblings 8 apart -> same XCD (round-robin %8)
  int v = bid & 7, cp = (bid >> 3) & 1, u = bid >> 4;
  int unit = u * 8 + v;            // [0,1024)
  int pair = unit >> 8;            // (pz,py)
  int rowGroup = unit & 255;
  int pz = pair >> 1, py = pair & 1;
  int p = pz * 4 + py * 2 + cp;
  int rowIdx = rowGroup * 4 + wv;  // [0,1024)
  int z = rowIdx >> 5, y = rowIdx & 31;

  f32x16 acc[3];
#pragma unroll
  for (int nt = 0; nt < 3; ++nt) acc[nt] = (f32x16)0.f;

  const uint4* W4 = (const uint4*)W_sw;
  int wph = p * 6144;  // uint4 index base for this phase

#pragma unroll
  for (int t = 0; t < 8; ++t) {
    int jz = (t >> 2) & 1, jy = (t >> 1) & 1, jx = t & 1;
    int zi = z + jz - 1 + pz;
    int yi = y + jy - 1 + py;
    if ((unsigned)zi >= 32u || (unsigned)yi >= 32u) continue;  // wave-uniform
    const unsigned short* xrow =
        xTpad + (zi * 32 + yi) * ROWS + (n + jx + cp) * 64 + h * 8;
    int wb = wph + t * 768;  // (t*4+q)*192 + nt*64 + lane
#pragma unroll
    for (int q = 0; q < 4; ++q) {
      bf16x8 bfrag = bc16(*(const uint4*)(xrow + q * 16));
      const uint4* wf = W4 + wb + q * 192 + lane;
      bf16x8 a0 = bc16(wf[0]);
      bf16x8 a1 = bc16(wf[64]);
      bf16x8 a2 = bc16(wf[128]);
      acc[0] = __builtin_amdgcn_mfma_f32_32x32x16_bf16(a0, bfrag, acc[0], 0, 0, 0);
      acc[1] = __builtin_amdgcn_mfma_f32_32x32x16_bf16(a1, bfrag, acc[1], 0, 0, 0);
      acc[2] = __builtin_amdgcn_mfma_f32_32x32x16_bf16(a2, bfrag, acc[2], 0, 0, 0);
    }
  }

  // ---- epilogue: BN1+ReLU, pack to bf16 pairs -------------------------------
  float b1r[16];
#pragma unroll
  for (int r = 0; r < 16; ++r) b1r[r] = bias1f[(r & 3) + 8 * (r >> 2) + 4 * h];
  unsigned uu[3][8];
#pragma unroll
  for (int nt = 0; nt < 3; ++nt)
#pragma unroll
    for (int i = 0; i < 8; ++i) {
      float v0 = fmaxf(acc[nt][2 * i] + b1r[2 * i], 0.f);
      float v1 = fmaxf(acc[nt][2 * i + 1] + b1r[2 * i + 1], 0.f);
      uu[nt][i] = (unsigned)f2bf(v0) | ((unsigned)f2bf(v1) << 16);
    }

  // ---- fused combine GEMM (K=96) via half-wave swaps ------------------------
  // Step s2 = 2e+f, half h needs channels 16e+8h+[0,8): first 4 from quad
  // (2e+h) of half 0 semantics... concretely: USE own quad 2e+h, SEND quad
  // 2e+(1-h) (so receiver gets sender's quad 2e+h_receiver).
  f32x16 c2 = (f32x16)0.f;
  const uint4* W24 = (const uint4*)W2_sw;
#pragma unroll
  for (int s2 = 0; s2 < 6; ++s2) {
    int nt = s2 >> 1;
    int e = s2 & 1;
    int gOwn = 2 * e + h;
    int gSend = 2 * e + (1 - h);
    unsigned o0 = uu[nt][2 * gOwn], o1 = uu[nt][2 * gOwn + 1];
    unsigned s0v = uu[nt][2 * gSend], s1v = uu[nt][2 * gSend + 1];
    unsigned x0 = (unsigned)__shfl_xor((int)s0v, 32, 64);
    unsigned x1 = (unsigned)__shfl_xor((int)s1v, 32, 64);
    uint4 fv = h ? make_uint4(x0, x1, o0, o1) : make_uint4(o0, o1, x0, x1);
    bf16x8 b2 = bc16(fv);
    bf16x8 a2 = bc16(W24[s2 * 64 + lane]);
    c2 = __builtin_amdgcn_mfma_f32_32x32x16_bf16(a2, b2, c2, 0, 0, 0);
  }

  // ---- BN2+ReLU, store ------------------------------------------------------
  int Z = 2 * z + pz, Y = 2 * y + py;
  float* ob = out + Z * 4096 + Y * 64 + 2 * n + cp;
#pragma unroll
  for (int r = 0; r < 16; ++r) {
    int ch = (r & 3) + 8 * (r >> 2) + 4 * h;
    ob[(size_t)ch << 18] = fmaxf(c2[r] + bias2f[ch], 0.f);
  }
}

// ---------------------------------------------------------------------------
extern "C" void kernel_launch(void* const* d_in, const int* in_sizes, int n_in,
                              void* d_out, int out_size, void* d_ws, size_t ws_size,
                              hipStream_t stream) {
  (void)in_sizes; (void)n_in; (void)out_size; (void)ws_size;
  const float* x      = (const float*)d_in[0];
  const float* w_def  = (const float*)d_in[1];
  const float* b_def  = (const float*)d_in[2];
  const float* bn1_g  = (const float*)d_in[3];
  const float* bn1_b  = (const float*)d_in[4];
  const float* bn1_m  = (const float*)d_in[5];
  const float* bn1_v  = (const float*)d_in[6];
  const float* w_comb = (const float*)d_in[7];
  const float* b_comb = (const float*)d_in[8];
  const float* bn2_g  = (const float*)d_in[9];
  const float* bn2_b  = (const float*)d_in[10];
  const float* bn2_m  = (const float*)d_in[11];
  const float* bn2_v  = (const float*)d_in[12];

  char* ws = (char*)d_ws;
  unsigned short* xTpad = (unsigned short*)(ws);            // 4,456,448 B
  unsigned short* W_sw  = (unsigned short*)(ws + 4456448);  //   786,432 B
  unsigned short* W2sw  = (unsigned short*)(ws + 5242880);  //     6,144 B
  float* bias1 = (float*)(ws + 5249024);                    //       128 B
  float* bias2 = (float*)(ws + 5249152);                    //       128 B
  float* out = (float*)d_out;

  hipLaunchKernelGGL(k_prep, dim3(2049), dim3(256), 0, stream,
                     x, w_def, b_def, bn1_g, bn1_b, bn1_m, bn1_v,
                     w_comb, b_comb, bn2_g, bn2_b, bn2_m, bn2_v,
                     xTpad, W_sw, W2sw, bias1, bias2);
  hipLaunchKernelGGL(k_main, dim3(2048), dim3(256), 0, stream,
                     xTpad, W_sw, W2sw, bias1, bias2, out);
}